// Round 14
// baseline (197.701 us; speedup 1.0000x reference)
//
#include <hip/hip_runtime.h>
#include <hip/hip_bf16.h>
#include <math.h>

// FrequencySelfAttention3: B=8, C=128, H=W=64 (N=4096 tokens).
// ifft2(|F|·w_c·e^{i·angle F}) = w_c·x  -> FFT branch is a per-channel scale.
// R21: decouple R20's two changes. R20 = {q=64 + DMA staging} + {S=4 merge}:
// flash 100->95.7 but merge +6 (32MB Op) -- net wash vs R16's 192.0. Budget
// model: fixed harness overhead ~75us (invariant across kernel-count), flash
// ~96, proj ~10, merge 7(S=2)/13(S=4). This round: R16 structure (q=32/wave,
// S=2 halves, grid 512, merge 16MB) + R20's PROVEN global_load_lds dbuf
// kv=32 staging (frees 32 T14-prefetch VGPRs, 1 barrier/kv32 vs 2/kv64; K/V
// DMA source-swizzle byte-identical to R20, HW-verified). LDS 43008. Watch:
// VGPR<=84 + Occupancy~26% = R12's 3-WG/CU signature -> next round S=3/768.

typedef __bf16 bf16;
typedef _Float16 f16;
typedef __bf16 bf16x8 __attribute__((ext_vector_type(8)));
typedef __bf16 bf16x4 __attribute__((ext_vector_type(4)));
typedef __bf16 bf16x2 __attribute__((ext_vector_type(2)));
typedef _Float16 f16x8 __attribute__((ext_vector_type(8)));
typedef float  f32x4  __attribute__((ext_vector_type(4)));
typedef unsigned int u32x4 __attribute__((ext_vector_type(4)));

#define MFMA16(a, b, c) __builtin_amdgcn_mfma_f32_16x16x32_bf16((a), (b), (c), 0, 0, 0)

static constexpr int BATCH = 8;
static constexpr int CH    = 128;
static constexpr int NTOK  = 4096;
static constexpr int XS    = 136;   // proj stage stride (bf16 elems)
static constexpr int VS    = 72;    // proj V-stage stride
static constexpr int PS2   = 40;    // flash P stride (80 B, 16B-aligned)
static constexpr int MS    = 136;   // merge O row stride
static constexpr float FIXM = 8.0f; // fixed max, exp2 domain (|S*log2e| <~ 7)

// async global->LDS DMA, 16B per lane; dest = wave-uniform base + lane*16
__device__ inline void dma16(const bf16* g, bf16* l) {
  __builtin_amdgcn_global_load_lds(
      (__attribute__((address_space(1))) unsigned int*)g,
      (__attribute__((address_space(3))) unsigned int*)l, 16, 0, 0);
}

// fp32 row -> bf16x8 fragment with scale (weights are L2-hot)
__device__ inline bf16x8 cvt8(const float* p, float s) {
  f32x4 a = *(const f32x4*)p;
  f32x4 b = *(const f32x4*)(p + 4);
  bf16x8 r;
  #pragma unroll
  for (int i = 0; i < 4; ++i) { r[i] = (bf16)(a[i] * s); r[4 + i] = (bf16)(b[i] * s); }
  return r;
}

// ---------------- kernel 1: QKV projections (R16-exact) --------------------
__global__ __launch_bounds__(512) void proj_kernel(
    const float* __restrict__ x, const float* __restrict__ fw,
    const float* __restrict__ wq, const float* __restrict__ wk,
    const float* __restrict__ wv,
    const float* __restrict__ bq, const float* __restrict__ bk,
    const float* __restrict__ bv,
    bf16* __restrict__ Qt, bf16* __restrict__ Kt, bf16* __restrict__ Vt,
    float qscale)
{
  const int wg = blockIdx.x;
  const int b = wg >> 6, tile = wg & 63;
  const int t = threadIdx.x;
  const int w = t >> 6, lane = t & 63, quad = lane >> 4, l15 = lane & 15;

  __shared__ bf16 stage[128 * VS];      // 18432 B; aliases Xt[64][XS] (17408)

  const float* xb = x + (size_t)b * CH * NTOK + tile * 64;
  #pragma unroll
  for (int i = 0; i < 8; ++i) {
    int c = (i * 8 + w) * 2;            // channel pair
    float f0 = fw[c], f1 = fw[c + 1];
    float x0 = xb[(size_t)c * NTOK + lane] * f0;
    float x1 = xb[(size_t)(c + 1) * NTOK + lane] * f1;
    bf16x2 pk; pk.x = (bf16)x0; pk.y = (bf16)x1;
    *(bf16x2*)(&stage[lane * XS + c]) = pk;
  }
  __syncthreads();

  bf16x8 xfrag[4][4];
  #pragma unroll
  for (int st = 0; st < 4; ++st)
    #pragma unroll
    for (int ks = 0; ks < 4; ++ks)
      xfrag[st][ks] = *(const bf16x8*)(&stage[(st * 16 + l15) * XS + ks * 32 + quad * 8]);

  const size_t wrow = (size_t)(w * 16 + l15) * CH;
  const int tokb = tile * 64;
  __syncthreads();                      // all xfrag in regs; stage reusable

  // ---- Q ----
  {
    bf16x8 qw[4];
    #pragma unroll
    for (int ks = 0; ks < 4; ++ks) qw[ks] = cvt8(wq + wrow + ks * 32 + quad * 8, qscale);
    f32x4 acc[4];
    #pragma unroll
    for (int st = 0; st < 4; ++st) acc[st] = (f32x4){0.f, 0.f, 0.f, 0.f};
    #pragma unroll
    for (int ks = 0; ks < 4; ++ks)
      #pragma unroll
      for (int st = 0; st < 4; ++st)
        acc[st] = MFMA16(qw[ks], xfrag[st][ks], acc[st]);
    float bias[4];
    #pragma unroll
    for (int r = 0; r < 4; ++r) bias[r] = bq[w * 16 + quad * 4 + r] * qscale;
    #pragma unroll
    for (int st = 0; st < 4; ++st) {
      bf16x4 o;
      #pragma unroll
      for (int r = 0; r < 4; ++r) o[r] = (bf16)(acc[st][r] + bias[r]);
      *(bf16x4*)(&stage[(st * 16 + l15) * XS + w * 16 + quad * 4]) = o;
    }
    __syncthreads();
    #pragma unroll
    for (int p = 0; p < 2; ++p) {
      int idx = p * 512 + t, row = idx >> 4, ch = (idx & 15) * 8;
      u32x4 d = *(const u32x4*)(&stage[row * XS + ch]);
      *(u32x4*)(&Qt[((size_t)b * NTOK + tokb + row) * CH + ch]) = d;
    }
    __syncthreads();
  }
  // ---- K ----
  {
    bf16x8 kw[4];
    #pragma unroll
    for (int ks = 0; ks < 4; ++ks) kw[ks] = cvt8(wk + wrow + ks * 32 + quad * 8, 1.0f);
    f32x4 acc[4];
    #pragma unroll
    for (int st = 0; st < 4; ++st) acc[st] = (f32x4){0.f, 0.f, 0.f, 0.f};
    #pragma unroll
    for (int ks = 0; ks < 4; ++ks)
      #pragma unroll
      for (int st = 0; st < 4; ++st)
        acc[st] = MFMA16(kw[ks], xfrag[st][ks], acc[st]);
    float bias[4];
    #pragma unroll
    for (int r = 0; r < 4; ++r) bias[r] = bk[w * 16 + quad * 4 + r];
    #pragma unroll
    for (int st = 0; st < 4; ++st) {
      bf16x4 o;
      #pragma unroll
      for (int r = 0; r < 4; ++r) o[r] = (bf16)(acc[st][r] + bias[r]);
      *(bf16x4*)(&stage[(st * 16 + l15) * XS + w * 16 + quad * 4]) = o;
    }
    __syncthreads();
    #pragma unroll
    for (int p = 0; p < 2; ++p) {
      int idx = p * 512 + t, row = idx >> 4, ch = (idx & 15) * 8;
      u32x4 d = *(const u32x4*)(&stage[row * XS + ch]);
      *(u32x4*)(&Kt[((size_t)b * NTOK + tokb + row) * CH + ch]) = d;
    }
    __syncthreads();
  }
  // ---- V ----
  {
    bf16x8 vw[4];
    #pragma unroll
    for (int ks = 0; ks < 4; ++ks) vw[ks] = cvt8(wv + wrow + ks * 32 + quad * 8, 1.0f);
    f32x4 acc[4];
    #pragma unroll
    for (int st = 0; st < 4; ++st) acc[st] = (f32x4){0.f, 0.f, 0.f, 0.f};
    #pragma unroll
    for (int ks = 0; ks < 4; ++ks)
      #pragma unroll
      for (int st = 0; st < 4; ++st)
        acc[st] = MFMA16(xfrag[st][ks], vw[ks], acc[st]);
    float bias = bv[w * 16 + l15];
    #pragma unroll
    for (int st = 0; st < 4; ++st) {
      bf16x4 o;
      #pragma unroll
      for (int r = 0; r < 4; ++r) o[r] = (bf16)(acc[st][r] + bias);
      *(bf16x4*)(&stage[(w * 16 + l15) * VS + st * 16 + quad * 4]) = o;
    }
    __syncthreads();
    #pragma unroll
    for (int p = 0; p < 2; ++p) {
      int idx = p * 512 + t, row = idx >> 3, tk = (idx & 7) * 8;
      u32x4 d = *(const u32x4*)(&stage[row * VS + tk]);
      *(u32x4*)(&Vt[((size_t)b * CH + row) * NTOK + tokb + tk]) = d;
    }
  }
}

// ---------------- kernel 2: flash partial, q=32/wave, DMA-dbuf kv=32 -------
// Grid 512 = b(8) x half(2) x qt128(32). 256 thr. LDS 43008:
// buf0{K 8K|V 8K} buf1{K 8K|V 8K} P 10K. 64 kt-iters of kv=32.
__global__ __launch_bounds__(256, 2) void flash_part_kernel(
    const bf16* __restrict__ Qt, const bf16* __restrict__ Kt,
    const bf16* __restrict__ Vt, f16* __restrict__ Op, float* __restrict__ Lp)
{
  __shared__ __align__(16) char lds[43008];

  const int wg = blockIdx.x;
  const int b = wg >> 6, half = (wg >> 5) & 1, qt = wg & 31;
  const int t = threadIdx.x;
  const int w = t >> 6, lane = t & 63, quad = lane >> 4, l15 = lane & 15;
  const int swz = l15 & 7;

  bf16x8 qfrag[2][4];
  #pragma unroll
  for (int s2 = 0; s2 < 2; ++s2) {
    const bf16* qb = Qt + ((size_t)b * NTOK + qt * 128 + w * 32 + s2 * 16 + l15) * CH;
    #pragma unroll
    for (int ks = 0; ks < 4; ++ks)
      qfrag[s2][ks] = *(const bf16x8*)(qb + ks * 32 + quad * 8);
  }

  f32x4 o_acc[2][8];
  #pragma unroll
  for (int s2 = 0; s2 < 2; ++s2)
    #pragma unroll
    for (int nt = 0; nt < 8; ++nt) o_acc[s2][nt] = (f32x4){0.f, 0.f, 0.f, 0.f};
  float lsum[2] = {0.f, 0.f};

  const bf16* kb = Kt + ((size_t)b * NTOK + half * 2048) * CH;
  const bf16* vb = Vt + (size_t)b * CH * NTOK + half * 2048;

  // DMA sources: pre-swizzled GLOBAL addresses, linear LDS dest (m173;
  // byte-identical scheme to R20, HW-verified).
  // K slot(row 0..31, cb 0..15): LDS row*256B+cb*16B = K[row][(cb^(row&7))*8..+8]
  // V slot(ch 0..127, cb 0..3): LDS ch*64B+cb*16B = V[ch][kvb*8..+8],
  //   kvb = (cb + ((ch>>2)&3)) & 3
  const bf16* kdma[2]; const bf16* vdma[2];
  #pragma unroll
  for (int jj = 0; jj < 2; ++jj) {
    int slot = w * 128 + jj * 64 + lane;
    int krow = slot >> 4, kcb = slot & 15;
    kdma[jj] = kb + (size_t)krow * CH + ((kcb ^ (krow & 7)) * 8);
    int vch = slot >> 2, vcb = slot & 3;
    vdma[jj] = vb + (size_t)vch * NTOK + (((vcb + ((vch >> 2) & 3)) & 3) * 8);
  }

  bf16* Pw = (bf16*)(lds + 32768) + w * 32 * PS2;   // per-wave [32 q][PS2]

  // prologue: DMA tile 0 -> buffer 0
  {
    bf16* dK = (bf16*)(lds) + w * 1024;
    bf16* dV = (bf16*)(lds + 8192) + w * 1024;
    dma16(kdma[0], dK); dma16(kdma[1], dK + 512);
    dma16(vdma[0], dV); dma16(vdma[1], dV + 512);
    kdma[0] += 32 * CH; kdma[1] += 32 * CH;
    vdma[0] += 32;      vdma[1] += 32;
  }
  __syncthreads();

  for (int kt = 0; kt < 64; ++kt) {
    const char* bK = lds + ((kt & 1) ? 16384 : 0);
    const char* bV = bK + 8192;

    // issue next tile's DMA into the other buffer (its readers finished at
    // the previous barrier); the barrier at loop end drains vmcnt.
    if (kt + 1 < 64) {
      bf16* nK = (bf16*)(lds + ((kt & 1) ? 0 : 16384)) + w * 1024;
      bf16* nV = nK + 4096;             // +8192 B = V region of that buffer
      dma16(kdma[0], nK); dma16(kdma[1], nK + 512);
      dma16(vdma[0], nV); dma16(vdma[1], nV + 512);
      kdma[0] += 32 * CH; kdma[1] += 32 * CH;
      vdma[0] += 32;      vdma[1] += 32;
    }

    // ---- S^T = K Q^T per 16-kv strip (qscale*L2E folded into Wq) ----
    #pragma unroll
    for (int mt = 0; mt < 2; ++mt) {
      f32x4 s[2];
      s[0] = (f32x4){0.f, 0.f, 0.f, 0.f};
      s[1] = (f32x4){0.f, 0.f, 0.f, 0.f};
      #pragma unroll
      for (int ks = 0; ks < 4; ++ks) {
        bf16x8 kfr = *(const bf16x8*)(bK + (mt * 16 + l15) * 256 + (((ks * 4 + quad) ^ swz) * 16));
        s[0] = MFMA16(kfr, qfrag[0][ks], s[0]);
        s[1] = MFMA16(kfr, qfrag[1][ks], s[1]);
      }
      // p = exp2(s - 8): per-lane; P write b64 (kv quad*4..+3 contiguous)
      #pragma unroll
      for (int s2 = 0; s2 < 2; ++s2) {
        f32x4 v = s[s2];
        bf16x4 pk;
        float ps = 0.f;
        #pragma unroll
        for (int r = 0; r < 4; ++r) {
          float p = exp2f(v[r] - FIXM);
          ps += p;
          pk[r] = (bf16)p;
        }
        lsum[s2] += ps;
        *(bf16x4*)(Pw + (s2 * 16 + l15) * PS2 + mt * 16 + quad * 4) = pk;
      }
    }
    // P wave-private: wave-internal lgkmcnt orders write->read (no barrier)

    bf16x8 pfrag[2];
    #pragma unroll
    for (int s2 = 0; s2 < 2; ++s2)
      pfrag[s2] = *(const bf16x8*)(Pw + (s2 * 16 + l15) * PS2 + quad * 8);

    // ---- O += P V (V-frag shared across both q subtiles) ----
    const int vrot = (l15 >> 2) & 3;
    const char* vrb = bV + l15 * 64 + (((quad - vrot) & 3) * 16);
    #pragma unroll
    for (int nt = 0; nt < 8; ++nt) {
      bf16x8 vfr = *(const bf16x8*)(vrb + nt * 1024);
      o_acc[0][nt] = MFMA16(pfrag[0], vfr, o_acc[0][nt]);
      o_acc[1][nt] = MFMA16(pfrag[1], vfr, o_acc[1][nt]);
    }

    __syncthreads();                    // drains vmcnt (next tile landed)
  }

  // write unnormalized partial O (fp16) + partial row sums (R16-exact)
  const size_t obase = ((size_t)(b * 2 + half) * NTOK + qt * 128 + w * 32) * CH;
  #pragma unroll
  for (int s2 = 0; s2 < 2; ++s2)
    #pragma unroll
    for (int nt = 0; nt < 8; ++nt)
      #pragma unroll
      for (int r = 0; r < 4; ++r) {
        int row = s2 * 16 + quad * 4 + r;
        Op[obase + (size_t)row * CH + nt * 16 + l15] = (f16)o_acc[s2][nt][r];
      }
  #pragma unroll
  for (int s2 = 0; s2 < 2; ++s2) {
    float v = lsum[s2];
    v += __shfl_xor(v, 16);
    v += __shfl_xor(v, 32);
    if (quad == 0)
      Lp[(size_t)(b * 2 + half) * NTOK + qt * 128 + w * 32 + s2 * 16 + l15] = v;
  }
}

// ---------------- kernel 3: merge halves + Wo projection (R16-exact) -------
__global__ __launch_bounds__(256) void merge_kernel(
    const f16* __restrict__ Op, const float* __restrict__ Lp,
    const float* __restrict__ wo, const float* __restrict__ bo,
    float* __restrict__ out)
{
  const int wg = blockIdx.x;            // 512 = b(8) x tile(64)
  const int b = wg >> 6, tile = wg & 63;
  const int t = threadIdx.x;
  const int w = t >> 6, lane = t & 63, quad = lane >> 4, l15 = lane & 15;

  __shared__ bf16 ldsO[64 * MS];        // [tok][c], padded stride (272 B)

  const f16* o0 = Op + ((size_t)(b * 2 + 0) * NTOK + tile * 64) * CH;
  const f16* o1 = Op + ((size_t)(b * 2 + 1) * NTOK + tile * 64) * CH;
  const float* lp0 = Lp + (size_t)(b * 2 + 0) * NTOK + tile * 64;
  const float* lp1 = Lp + (size_t)(b * 2 + 1) * NTOK + tile * 64;

  #pragma unroll
  for (int i = 0; i < 4; ++i) {
    int idx = t + i * 256;              // 1024 chunks of 8 elems
    int row = idx >> 4, cb = idx & 15;
    float inv = 1.0f / (lp0[row] + lp1[row]);
    f16x8 a0 = *(const f16x8*)(o0 + (size_t)row * CH + cb * 8);
    f16x8 a1 = *(const f16x8*)(o1 + (size_t)row * CH + cb * 8);
    bf16 tmp[8];
    #pragma unroll
    for (int j = 0; j < 8; ++j)
      tmp[j] = (bf16)(((float)a0[j] + (float)a1[j]) * inv);
    *(u32x4*)(&ldsO[row * MS + cb * 8]) = *(u32x4*)tmp;
  }
  __syncthreads();

  #pragma unroll
  for (int mi = 0; mi < 2; ++mi) {
    int mt = w * 2 + mi;
    f32x4 facc[4];
    #pragma unroll
    for (int nt = 0; nt < 4; ++nt) facc[nt] = (f32x4){0.f, 0.f, 0.f, 0.f};
    #pragma unroll
    for (int ks = 0; ks < 4; ++ks) {
      bf16x8 afr = cvt8(wo + (size_t)(mt * 16 + l15) * CH + ks * 32 + quad * 8, 1.0f);
      #pragma unroll
      for (int nt = 0; nt < 4; ++nt) {
        bf16x8 bfr = *(const bf16x8*)(&ldsO[(nt * 16 + l15) * MS + ks * 32 + quad * 8]);
        facc[nt] = MFMA16(afr, bfr, facc[nt]);
      }
    }
    #pragma unroll
    for (int nt = 0; nt < 4; ++nt) {
      int n = tile * 64 + nt * 16 + l15;
      #pragma unroll
      for (int r = 0; r < 4; ++r) {
        int o = mt * 16 + quad * 4 + r;
        out[((size_t)b * CH + o) * NTOK + n] = facc[nt][r] + bo[o];
      }
    }
  }
}

// ---------------- launch ---------------------------------------------------
extern "C" void kernel_launch(void* const* d_in, const int* in_sizes, int n_in,
                              void* d_out, int out_size, void* d_ws, size_t ws_size,
                              hipStream_t stream)
{
  const float* x  = (const float*)d_in[0];
  const float* fw = (const float*)d_in[1];
  const float* wq = (const float*)d_in[2];
  const float* bq = (const float*)d_in[3];
  const float* wk = (const float*)d_in[4];
  const float* bk = (const float*)d_in[5];
  const float* wv = (const float*)d_in[6];
  const float* bv = (const float*)d_in[7];
  const float* wo = (const float*)d_in[8];
  const float* bo = (const float*)d_in[9];
  float* out = (float*)d_out;

  char* ws = (char*)d_ws;
  bf16*  Qt  = (bf16*)ws;                              // 8 MB
  bf16*  Kt  = Qt + (size_t)BATCH * NTOK * CH;         // 8 MB
  bf16*  Vt  = Kt + (size_t)BATCH * NTOK * CH;         // 8 MB
  f16*   Op  = (f16*)(ws + 3ull * 8388608);            // 16 MB: [2B][N][C] fp16
  float* Lp  = (float*)((char*)Op + 16777216);         // 256 KB

  // 1/sqrt(128) * log2(e): exp2-domain scale folded into Wq/bq
  const float qscale = 0.08838834764831845f * 1.44269504f;

  proj_kernel<<<512, 512, 0, stream>>>(x, fw, wq, wk, wv,
                                       bq, bk, bv, Qt, Kt, Vt, qscale);
  flash_part_kernel<<<512, 256, 0, stream>>>(Qt, Kt, Vt, Op, Lp);
  merge_kernel<<<512, 256, 0, stream>>>(Op, Lp, wo, bo, out);
}

// Round 15
// 194.597 us; speedup vs baseline: 1.0159x; 1.0159x over previous
//
#include <hip/hip_runtime.h>
#include <hip/hip_bf16.h>
#include <math.h>

// FrequencySelfAttention3: B=8, C=128, H=W=64 (N=4096 tokens).
// ifft2(|F|·w_c·e^{i·angle F}) = w_c·x  -> FFT branch is a per-channel scale.
// R22: occupancy, with ALL constraints satisfied at once. Model (from 11
// measured rounds): unified VGPR+AGPR granule ~16 -> 3 waves/SIMD needs
// total <= 160. R16 flash = 104+64acc = 168 -> hard 2-WG cap (R14/R15's
// failures). R12's spilled build = 148 -> 3 WGs landed (26% occ). R21's DMA
// flash = 80+64 = 144 <= 160: first spill-free 3-wave-capable structure --
// it just never had grid+bounds to use it. This round: R21 flash body
// (byte-identical DMA kv=32 dbuf) + __launch_bounds__(256,3) (cap 168 >=
// 144 used -> no spill, unlike R13 whose live set exceeded the cap) + S=3
// uneven slabs (43/43/42 kv32-tiles, R15-proven indexing) -> grid 768 =
// exactly 3 WG/CU (LDS 43008x3 = 129K <= 160K). Merge = R13 nslab (24 MB).
// Proj = R16-exact. WATCH: WRITE>=100MB = spill -> revert; occ ~19% =
// granule model wrong -> R16 plateau.

typedef __bf16 bf16;
typedef _Float16 f16;
typedef __bf16 bf16x8 __attribute__((ext_vector_type(8)));
typedef __bf16 bf16x4 __attribute__((ext_vector_type(4)));
typedef __bf16 bf16x2 __attribute__((ext_vector_type(2)));
typedef _Float16 f16x8 __attribute__((ext_vector_type(8)));
typedef float  f32x4  __attribute__((ext_vector_type(4)));
typedef unsigned int u32x4 __attribute__((ext_vector_type(4)));

#define MFMA16(a, b, c) __builtin_amdgcn_mfma_f32_16x16x32_bf16((a), (b), (c), 0, 0, 0)

static constexpr int BATCH = 8;
static constexpr int CH    = 128;
static constexpr int NTOK  = 4096;
static constexpr int XS    = 136;   // proj stage stride (bf16 elems)
static constexpr int VS    = 72;    // proj V-stage stride
static constexpr int PS2   = 40;    // flash P stride (80 B, 16B-aligned)
static constexpr int MS    = 136;   // merge O row stride
static constexpr float FIXM = 8.0f; // fixed max, exp2 domain (|S*log2e| <~ 7)

// async global->LDS DMA, 16B per lane; dest = wave-uniform base + lane*16
__device__ inline void dma16(const bf16* g, bf16* l) {
  __builtin_amdgcn_global_load_lds(
      (__attribute__((address_space(1))) unsigned int*)g,
      (__attribute__((address_space(3))) unsigned int*)l, 16, 0, 0);
}

// fp32 row -> bf16x8 fragment with scale (weights are L2-hot)
__device__ inline bf16x8 cvt8(const float* p, float s) {
  f32x4 a = *(const f32x4*)p;
  f32x4 b = *(const f32x4*)(p + 4);
  bf16x8 r;
  #pragma unroll
  for (int i = 0; i < 4; ++i) { r[i] = (bf16)(a[i] * s); r[4 + i] = (bf16)(b[i] * s); }
  return r;
}

// ---------------- kernel 1: QKV projections (R16-exact) --------------------
__global__ __launch_bounds__(512) void proj_kernel(
    const float* __restrict__ x, const float* __restrict__ fw,
    const float* __restrict__ wq, const float* __restrict__ wk,
    const float* __restrict__ wv,
    const float* __restrict__ bq, const float* __restrict__ bk,
    const float* __restrict__ bv,
    bf16* __restrict__ Qt, bf16* __restrict__ Kt, bf16* __restrict__ Vt,
    float qscale)
{
  const int wg = blockIdx.x;
  const int b = wg >> 6, tile = wg & 63;
  const int t = threadIdx.x;
  const int w = t >> 6, lane = t & 63, quad = lane >> 4, l15 = lane & 15;

  __shared__ bf16 stage[128 * VS];      // 18432 B; aliases Xt[64][XS] (17408)

  const float* xb = x + (size_t)b * CH * NTOK + tile * 64;
  #pragma unroll
  for (int i = 0; i < 8; ++i) {
    int c = (i * 8 + w) * 2;            // channel pair
    float f0 = fw[c], f1 = fw[c + 1];
    float x0 = xb[(size_t)c * NTOK + lane] * f0;
    float x1 = xb[(size_t)(c + 1) * NTOK + lane] * f1;
    bf16x2 pk; pk.x = (bf16)x0; pk.y = (bf16)x1;
    *(bf16x2*)(&stage[lane * XS + c]) = pk;
  }
  __syncthreads();

  bf16x8 xfrag[4][4];
  #pragma unroll
  for (int st = 0; st < 4; ++st)
    #pragma unroll
    for (int ks = 0; ks < 4; ++ks)
      xfrag[st][ks] = *(const bf16x8*)(&stage[(st * 16 + l15) * XS + ks * 32 + quad * 8]);

  const size_t wrow = (size_t)(w * 16 + l15) * CH;
  const int tokb = tile * 64;
  __syncthreads();                      // all xfrag in regs; stage reusable

  // ---- Q ----
  {
    bf16x8 qw[4];
    #pragma unroll
    for (int ks = 0; ks < 4; ++ks) qw[ks] = cvt8(wq + wrow + ks * 32 + quad * 8, qscale);
    f32x4 acc[4];
    #pragma unroll
    for (int st = 0; st < 4; ++st) acc[st] = (f32x4){0.f, 0.f, 0.f, 0.f};
    #pragma unroll
    for (int ks = 0; ks < 4; ++ks)
      #pragma unroll
      for (int st = 0; st < 4; ++st)
        acc[st] = MFMA16(qw[ks], xfrag[st][ks], acc[st]);
    float bias[4];
    #pragma unroll
    for (int r = 0; r < 4; ++r) bias[r] = bq[w * 16 + quad * 4 + r] * qscale;
    #pragma unroll
    for (int st = 0; st < 4; ++st) {
      bf16x4 o;
      #pragma unroll
      for (int r = 0; r < 4; ++r) o[r] = (bf16)(acc[st][r] + bias[r]);
      *(bf16x4*)(&stage[(st * 16 + l15) * XS + w * 16 + quad * 4]) = o;
    }
    __syncthreads();
    #pragma unroll
    for (int p = 0; p < 2; ++p) {
      int idx = p * 512 + t, row = idx >> 4, ch = (idx & 15) * 8;
      u32x4 d = *(const u32x4*)(&stage[row * XS + ch]);
      *(u32x4*)(&Qt[((size_t)b * NTOK + tokb + row) * CH + ch]) = d;
    }
    __syncthreads();
  }
  // ---- K ----
  {
    bf16x8 kw[4];
    #pragma unroll
    for (int ks = 0; ks < 4; ++ks) kw[ks] = cvt8(wk + wrow + ks * 32 + quad * 8, 1.0f);
    f32x4 acc[4];
    #pragma unroll
    for (int st = 0; st < 4; ++st) acc[st] = (f32x4){0.f, 0.f, 0.f, 0.f};
    #pragma unroll
    for (int ks = 0; ks < 4; ++ks)
      #pragma unroll
      for (int st = 0; st < 4; ++st)
        acc[st] = MFMA16(kw[ks], xfrag[st][ks], acc[st]);
    float bias[4];
    #pragma unroll
    for (int r = 0; r < 4; ++r) bias[r] = bk[w * 16 + quad * 4 + r];
    #pragma unroll
    for (int st = 0; st < 4; ++st) {
      bf16x4 o;
      #pragma unroll
      for (int r = 0; r < 4; ++r) o[r] = (bf16)(acc[st][r] + bias[r]);
      *(bf16x4*)(&stage[(st * 16 + l15) * XS + w * 16 + quad * 4]) = o;
    }
    __syncthreads();
    #pragma unroll
    for (int p = 0; p < 2; ++p) {
      int idx = p * 512 + t, row = idx >> 4, ch = (idx & 15) * 8;
      u32x4 d = *(const u32x4*)(&stage[row * XS + ch]);
      *(u32x4*)(&Kt[((size_t)b * NTOK + tokb + row) * CH + ch]) = d;
    }
    __syncthreads();
  }
  // ---- V ----
  {
    bf16x8 vw[4];
    #pragma unroll
    for (int ks = 0; ks < 4; ++ks) vw[ks] = cvt8(wv + wrow + ks * 32 + quad * 8, 1.0f);
    f32x4 acc[4];
    #pragma unroll
    for (int st = 0; st < 4; ++st) acc[st] = (f32x4){0.f, 0.f, 0.f, 0.f};
    #pragma unroll
    for (int ks = 0; ks < 4; ++ks)
      #pragma unroll
      for (int st = 0; st < 4; ++st)
        acc[st] = MFMA16(xfrag[st][ks], vw[ks], acc[st]);
    float bias = bv[w * 16 + l15];
    #pragma unroll
    for (int st = 0; st < 4; ++st) {
      bf16x4 o;
      #pragma unroll
      for (int r = 0; r < 4; ++r) o[r] = (bf16)(acc[st][r] + bias);
      *(bf16x4*)(&stage[(w * 16 + l15) * VS + st * 16 + quad * 4]) = o;
    }
    __syncthreads();
    #pragma unroll
    for (int p = 0; p < 2; ++p) {
      int idx = p * 512 + t, row = idx >> 3, tk = (idx & 7) * 8;
      u32x4 d = *(const u32x4*)(&stage[row * VS + tk]);
      *(u32x4*)(&Vt[((size_t)b * CH + row) * NTOK + tokb + tk]) = d;
    }
  }
}

// ---------------- kernel 2: flash partial, q=32/wave, DMA-dbuf kv=32 -------
// Grid = b(8) x slab(S) x qt128(32). LDS 43008 (x3 = 129K). Unified regs
// 80 VGPR + 64 AGPR = 144 <= 160 granule -> 3 waves/SIMD; (256,3) cap 168
// >= 144 -> no spill. ntile = per-slab kv-32 tile count (uneven).
__global__ __launch_bounds__(256, 3) void flash_part_kernel(
    const bf16* __restrict__ Qt, const bf16* __restrict__ Kt,
    const bf16* __restrict__ Vt, f16* __restrict__ Op, float* __restrict__ Lp,
    int nslab, int base, int rem)
{
  __shared__ __align__(16) char lds[43008];

  const int wg = blockIdx.x;
  const int qt = wg & 31;
  const int slab = (wg >> 5) % nslab;
  const int b = wg / (nslab * 32);
  const int ntile = base + (slab < rem ? 1 : 0);        // kv-32 tiles
  const int koff  = (slab * base + (slab < rem ? slab : rem)) * 32;
  const int t = threadIdx.x;
  const int w = t >> 6, lane = t & 63, quad = lane >> 4, l15 = lane & 15;
  const int swz = l15 & 7;

  bf16x8 qfrag[2][4];
  #pragma unroll
  for (int s2 = 0; s2 < 2; ++s2) {
    const bf16* qb = Qt + ((size_t)b * NTOK + qt * 128 + w * 32 + s2 * 16 + l15) * CH;
    #pragma unroll
    for (int ks = 0; ks < 4; ++ks)
      qfrag[s2][ks] = *(const bf16x8*)(qb + ks * 32 + quad * 8);
  }

  f32x4 o_acc[2][8];
  #pragma unroll
  for (int s2 = 0; s2 < 2; ++s2)
    #pragma unroll
    for (int nt = 0; nt < 8; ++nt) o_acc[s2][nt] = (f32x4){0.f, 0.f, 0.f, 0.f};
  float lsum[2] = {0.f, 0.f};

  const bf16* kb = Kt + ((size_t)b * NTOK + koff) * CH;
  const bf16* vb = Vt + (size_t)b * CH * NTOK + koff;

  // DMA sources: pre-swizzled GLOBAL addresses, linear LDS dest (m173;
  // byte-identical scheme to R20/R21, HW-verified).
  // K slot(row 0..31, cb 0..15): LDS row*256B+cb*16B = K[row][(cb^(row&7))*8..+8]
  // V slot(ch 0..127, cb 0..3): LDS ch*64B+cb*16B = V[ch][kvb*8..+8],
  //   kvb = (cb + ((ch>>2)&3)) & 3
  const bf16* kdma[2]; const bf16* vdma[2];
  #pragma unroll
  for (int jj = 0; jj < 2; ++jj) {
    int slot = w * 128 + jj * 64 + lane;
    int krow = slot >> 4, kcb = slot & 15;
    kdma[jj] = kb + (size_t)krow * CH + ((kcb ^ (krow & 7)) * 8);
    int vch = slot >> 2, vcb = slot & 3;
    vdma[jj] = vb + (size_t)vch * NTOK + (((vcb + ((vch >> 2) & 3)) & 3) * 8);
  }

  bf16* Pw = (bf16*)(lds + 32768) + w * 32 * PS2;   // per-wave [32 q][PS2]

  // prologue: DMA tile 0 -> buffer 0
  {
    bf16* dK = (bf16*)(lds) + w * 1024;
    bf16* dV = (bf16*)(lds + 8192) + w * 1024;
    dma16(kdma[0], dK); dma16(kdma[1], dK + 512);
    dma16(vdma[0], dV); dma16(vdma[1], dV + 512);
    kdma[0] += 32 * CH; kdma[1] += 32 * CH;
    vdma[0] += 32;      vdma[1] += 32;
  }
  __syncthreads();

  for (int kt = 0; kt < ntile; ++kt) {
    const char* bK = lds + ((kt & 1) ? 16384 : 0);
    const char* bV = bK + 8192;

    // issue next tile's DMA into the other buffer (its readers finished at
    // the previous barrier); the barrier at loop end drains vmcnt.
    if (kt + 1 < ntile) {
      bf16* nK = (bf16*)(lds + ((kt & 1) ? 0 : 16384)) + w * 1024;
      bf16* nV = nK + 4096;             // +8192 B = V region of that buffer
      dma16(kdma[0], nK); dma16(kdma[1], nK + 512);
      dma16(vdma[0], nV); dma16(vdma[1], nV + 512);
      kdma[0] += 32 * CH; kdma[1] += 32 * CH;
      vdma[0] += 32;      vdma[1] += 32;
    }

    // ---- S^T = K Q^T per 16-kv strip (qscale*L2E folded into Wq) ----
    #pragma unroll
    for (int mt = 0; mt < 2; ++mt) {
      f32x4 s[2];
      s[0] = (f32x4){0.f, 0.f, 0.f, 0.f};
      s[1] = (f32x4){0.f, 0.f, 0.f, 0.f};
      #pragma unroll
      for (int ks = 0; ks < 4; ++ks) {
        bf16x8 kfr = *(const bf16x8*)(bK + (mt * 16 + l15) * 256 + (((ks * 4 + quad) ^ swz) * 16));
        s[0] = MFMA16(kfr, qfrag[0][ks], s[0]);
        s[1] = MFMA16(kfr, qfrag[1][ks], s[1]);
      }
      // p = exp2(s - 8): per-lane; P write b64 (kv quad*4..+3 contiguous)
      #pragma unroll
      for (int s2 = 0; s2 < 2; ++s2) {
        f32x4 v = s[s2];
        bf16x4 pk;
        float ps = 0.f;
        #pragma unroll
        for (int r = 0; r < 4; ++r) {
          float p = exp2f(v[r] - FIXM);
          ps += p;
          pk[r] = (bf16)p;
        }
        lsum[s2] += ps;
        *(bf16x4*)(Pw + (s2 * 16 + l15) * PS2 + mt * 16 + quad * 4) = pk;
      }
    }
    // P wave-private: wave-internal lgkmcnt orders write->read (no barrier)

    bf16x8 pfrag[2];
    #pragma unroll
    for (int s2 = 0; s2 < 2; ++s2)
      pfrag[s2] = *(const bf16x8*)(Pw + (s2 * 16 + l15) * PS2 + quad * 8);

    // ---- O += P V (V-frag shared across both q subtiles) ----
    const int vrot = (l15 >> 2) & 3;
    const char* vrb = bV + l15 * 64 + (((quad - vrot) & 3) * 16);
    #pragma unroll
    for (int nt = 0; nt < 8; ++nt) {
      bf16x8 vfr = *(const bf16x8*)(vrb + nt * 1024);
      o_acc[0][nt] = MFMA16(pfrag[0], vfr, o_acc[0][nt]);
      o_acc[1][nt] = MFMA16(pfrag[1], vfr, o_acc[1][nt]);
    }

    __syncthreads();                    // drains vmcnt (next tile landed)
  }

  // write unnormalized partial O (fp16, plain stores) + partial row sums
  const size_t obase = ((size_t)(slab * BATCH + b) * NTOK + qt * 128 + w * 32) * CH;
  #pragma unroll
  for (int s2 = 0; s2 < 2; ++s2)
    #pragma unroll
    for (int nt = 0; nt < 8; ++nt)
      #pragma unroll
      for (int r = 0; r < 4; ++r) {
        int row = s2 * 16 + quad * 4 + r;
        Op[obase + (size_t)row * CH + nt * 16 + l15] = (f16)o_acc[s2][nt][r];
      }
  #pragma unroll
  for (int s2 = 0; s2 < 2; ++s2) {
    float v = lsum[s2];
    v += __shfl_xor(v, 16);
    v += __shfl_xor(v, 32);
    if (quad == 0)
      Lp[(size_t)(slab * BATCH + b) * NTOK + qt * 128 + w * 32 + s2 * 16 + l15] = v;
  }
}

// ---------------- kernel 3: merge S slabs + Wo projection (R13-proven) -----
__global__ __launch_bounds__(256) void merge_kernel(
    const f16* __restrict__ Op, const float* __restrict__ Lp,
    const float* __restrict__ wo, const float* __restrict__ bo,
    float* __restrict__ out, int nslab)
{
  const int wg = blockIdx.x;            // 512 = b(8) x tile(64)
  const int b = wg >> 6, tile = wg & 63;
  const int t = threadIdx.x;
  const int w = t >> 6, lane = t & 63, quad = lane >> 4, l15 = lane & 15;

  __shared__ bf16 ldsO[64 * MS];        // [tok][c], padded stride (272 B)

  const size_t slabO = (size_t)BATCH * NTOK * CH;   // f16 elems per slab
  const size_t slabL = (size_t)BATCH * NTOK;
  const f16* ob = Op + ((size_t)b * NTOK + tile * 64) * CH;
  const float* lp = Lp + (size_t)b * NTOK + tile * 64;

  #pragma unroll
  for (int i = 0; i < 4; ++i) {
    int idx = t + i * 256;              // 1024 chunks of 8 elems
    int row = idx >> 4, cb = idx & 15;
    float lsum_ = 0.f;
    for (int s = 0; s < nslab; ++s) lsum_ += lp[s * slabL + row];
    float acc8[8] = {0.f, 0.f, 0.f, 0.f, 0.f, 0.f, 0.f, 0.f};
    for (int s = 0; s < nslab; ++s) {
      f16x8 a = *(const f16x8*)(ob + s * slabO + (size_t)row * CH + cb * 8);
      #pragma unroll
      for (int j = 0; j < 8; ++j) acc8[j] += (float)a[j];
    }
    float inv = 1.0f / lsum_;
    bf16 tmp[8];
    #pragma unroll
    for (int j = 0; j < 8; ++j) tmp[j] = (bf16)(acc8[j] * inv);
    *(u32x4*)(&ldsO[row * MS + cb * 8]) = *(u32x4*)tmp;
  }
  __syncthreads();

  #pragma unroll
  for (int mi = 0; mi < 2; ++mi) {
    int mt = w * 2 + mi;
    f32x4 facc[4];
    #pragma unroll
    for (int nt = 0; nt < 4; ++nt) facc[nt] = (f32x4){0.f, 0.f, 0.f, 0.f};
    #pragma unroll
    for (int ks = 0; ks < 4; ++ks) {
      bf16x8 afr = cvt8(wo + (size_t)(mt * 16 + l15) * CH + ks * 32 + quad * 8, 1.0f);
      #pragma unroll
      for (int nt = 0; nt < 4; ++nt) {
        bf16x8 bfr = *(const bf16x8*)(&ldsO[(nt * 16 + l15) * MS + ks * 32 + quad * 8]);
        facc[nt] = MFMA16(afr, bfr, facc[nt]);
      }
    }
    #pragma unroll
    for (int nt = 0; nt < 4; ++nt) {
      int n = tile * 64 + nt * 16 + l15;
      #pragma unroll
      for (int r = 0; r < 4; ++r) {
        int o = mt * 16 + quad * 4 + r;
        out[((size_t)b * CH + o) * NTOK + n] = facc[nt][r] + bo[o];
      }
    }
  }
}

// ---------------- launch ---------------------------------------------------
extern "C" void kernel_launch(void* const* d_in, const int* in_sizes, int n_in,
                              void* d_out, int out_size, void* d_ws, size_t ws_size,
                              hipStream_t stream)
{
  const float* x  = (const float*)d_in[0];
  const float* fw = (const float*)d_in[1];
  const float* wq = (const float*)d_in[2];
  const float* bq = (const float*)d_in[3];
  const float* wk = (const float*)d_in[4];
  const float* bk = (const float*)d_in[5];
  const float* wv = (const float*)d_in[6];
  const float* bv = (const float*)d_in[7];
  const float* wo = (const float*)d_in[8];
  const float* bo = (const float*)d_in[9];
  float* out = (float*)d_out;

  char* ws = (char*)d_ws;
  bf16*  Qt  = (bf16*)ws;                              // 8 MB
  bf16*  Kt  = Qt + (size_t)BATCH * NTOK * CH;         // 8 MB
  bf16*  Vt  = Kt + (size_t)BATCH * NTOK * CH;         // 8 MB
  f16*   Op  = (f16*)(ws + 3ull * 8388608);            // S x 8 MB fp16 slabs

  // S=3 (grid 768 = one pass at 3 WG/CU) if ws allows, else S=2 (grid 512).
  const size_t qkv_bytes = 3ull * 8388608;
  const size_t need3 = qkv_bytes + 3ull * ((size_t)BATCH * NTOK * CH * 2 + (size_t)BATCH * NTOK * 4);
  const int S = (ws_size >= need3) ? 3 : 2;
  const int base = 128 / S, rem = 128 % S;             // kv-32 tiles per slab

  float* Lp = (float*)((char*)Op + (size_t)S * BATCH * NTOK * CH * 2);

  // 1/sqrt(128) * log2(e): exp2-domain scale folded into Wq/bq
  const float qscale = 0.08838834764831845f * 1.44269504f;

  proj_kernel<<<512, 512, 0, stream>>>(x, fw, wq, wk, wv,
                                       bq, bk, bv, Qt, Kt, Vt, qscale);
  flash_part_kernel<<<BATCH * S * 32, 256, 0, stream>>>(Qt, Kt, Vt, Op, Lp,
                                                        S, base, rem);
  merge_kernel<<<512, 256, 0, stream>>>(Op, Lp, wo, bo, out, S);
}

// Round 16
// 188.153 us; speedup vs baseline: 1.0507x; 1.0342x over previous
//
#include <hip/hip_runtime.h>
#include <hip/hip_bf16.h>
#include <math.h>

// FrequencySelfAttention3: B=8, C=128, H=W=64 (N=4096 tokens).
// ifft2(|F|·w_c·e^{i·angle F}) = w_c·x  -> FFT branch is a per-channel scale.
// R23: VALU diet on the R22 flash (3 WG/CU CONFIRMED: occ 26.3%, VGPR 80,
// no spill -- the <=160-unified-regs granule model verified). At 12
// waves/CU the kernel is VALU-issue-bound: VALUBusy 49.5 > MfmaUtil 30.7.
// Two cuts: (1) QK accumulator inits to -FIXM -> MFMA computes S-8, kills
// 8 v_sub/iter, free. (2) row-sums via MFMA vs ones-fragment (lacc =
// mfma(pfrag, ones, lacc); D cols all = rowsum) -> kills the 10-VALU
// ps/lsum chain, costs 2 MFMA/iter + 8 AGPR + 4 VGPR (unified ~156 <= 160,
// still 3 waves/SIMD -- WATCH occupancy stays ~26%). Epilogue reads
// lacc[r] at l15==0 lanes (D row = quad*4+r), no shfl reduce needed.
// Everything else R22-frozen: proj R16-exact, DMA kv=32 dbuf flash,
// S=3 uneven slabs grid 768, R13 nslab merge.

typedef __bf16 bf16;
typedef _Float16 f16;
typedef __bf16 bf16x8 __attribute__((ext_vector_type(8)));
typedef __bf16 bf16x4 __attribute__((ext_vector_type(4)));
typedef __bf16 bf16x2 __attribute__((ext_vector_type(2)));
typedef _Float16 f16x8 __attribute__((ext_vector_type(8)));
typedef float  f32x4  __attribute__((ext_vector_type(4)));
typedef unsigned int u32x4 __attribute__((ext_vector_type(4)));

#define MFMA16(a, b, c) __builtin_amdgcn_mfma_f32_16x16x32_bf16((a), (b), (c), 0, 0, 0)

static constexpr int BATCH = 8;
static constexpr int CH    = 128;
static constexpr int NTOK  = 4096;
static constexpr int XS    = 136;   // proj stage stride (bf16 elems)
static constexpr int VS    = 72;    // proj V-stage stride
static constexpr int PS2   = 40;    // flash P stride (80 B, 16B-aligned)
static constexpr int MS    = 136;   // merge O row stride
static constexpr float FIXM = 8.0f; // fixed max, exp2 domain (|S*log2e| <~ 7)

// async global->LDS DMA, 16B per lane; dest = wave-uniform base + lane*16
__device__ inline void dma16(const bf16* g, bf16* l) {
  __builtin_amdgcn_global_load_lds(
      (__attribute__((address_space(1))) unsigned int*)g,
      (__attribute__((address_space(3))) unsigned int*)l, 16, 0, 0);
}

// fp32 row -> bf16x8 fragment with scale (weights are L2-hot)
__device__ inline bf16x8 cvt8(const float* p, float s) {
  f32x4 a = *(const f32x4*)p;
  f32x4 b = *(const f32x4*)(p + 4);
  bf16x8 r;
  #pragma unroll
  for (int i = 0; i < 4; ++i) { r[i] = (bf16)(a[i] * s); r[4 + i] = (bf16)(b[i] * s); }
  return r;
}

// ---------------- kernel 1: QKV projections (R16-exact) --------------------
__global__ __launch_bounds__(512) void proj_kernel(
    const float* __restrict__ x, const float* __restrict__ fw,
    const float* __restrict__ wq, const float* __restrict__ wk,
    const float* __restrict__ wv,
    const float* __restrict__ bq, const float* __restrict__ bk,
    const float* __restrict__ bv,
    bf16* __restrict__ Qt, bf16* __restrict__ Kt, bf16* __restrict__ Vt,
    float qscale)
{
  const int wg = blockIdx.x;
  const int b = wg >> 6, tile = wg & 63;
  const int t = threadIdx.x;
  const int w = t >> 6, lane = t & 63, quad = lane >> 4, l15 = lane & 15;

  __shared__ bf16 stage[128 * VS];      // 18432 B; aliases Xt[64][XS] (17408)

  const float* xb = x + (size_t)b * CH * NTOK + tile * 64;
  #pragma unroll
  for (int i = 0; i < 8; ++i) {
    int c = (i * 8 + w) * 2;            // channel pair
    float f0 = fw[c], f1 = fw[c + 1];
    float x0 = xb[(size_t)c * NTOK + lane] * f0;
    float x1 = xb[(size_t)(c + 1) * NTOK + lane] * f1;
    bf16x2 pk; pk.x = (bf16)x0; pk.y = (bf16)x1;
    *(bf16x2*)(&stage[lane * XS + c]) = pk;
  }
  __syncthreads();

  bf16x8 xfrag[4][4];
  #pragma unroll
  for (int st = 0; st < 4; ++st)
    #pragma unroll
    for (int ks = 0; ks < 4; ++ks)
      xfrag[st][ks] = *(const bf16x8*)(&stage[(st * 16 + l15) * XS + ks * 32 + quad * 8]);

  const size_t wrow = (size_t)(w * 16 + l15) * CH;
  const int tokb = tile * 64;
  __syncthreads();                      // all xfrag in regs; stage reusable

  // ---- Q ----
  {
    bf16x8 qw[4];
    #pragma unroll
    for (int ks = 0; ks < 4; ++ks) qw[ks] = cvt8(wq + wrow + ks * 32 + quad * 8, qscale);
    f32x4 acc[4];
    #pragma unroll
    for (int st = 0; st < 4; ++st) acc[st] = (f32x4){0.f, 0.f, 0.f, 0.f};
    #pragma unroll
    for (int ks = 0; ks < 4; ++ks)
      #pragma unroll
      for (int st = 0; st < 4; ++st)
        acc[st] = MFMA16(qw[ks], xfrag[st][ks], acc[st]);
    float bias[4];
    #pragma unroll
    for (int r = 0; r < 4; ++r) bias[r] = bq[w * 16 + quad * 4 + r] * qscale;
    #pragma unroll
    for (int st = 0; st < 4; ++st) {
      bf16x4 o;
      #pragma unroll
      for (int r = 0; r < 4; ++r) o[r] = (bf16)(acc[st][r] + bias[r]);
      *(bf16x4*)(&stage[(st * 16 + l15) * XS + w * 16 + quad * 4]) = o;
    }
    __syncthreads();
    #pragma unroll
    for (int p = 0; p < 2; ++p) {
      int idx = p * 512 + t, row = idx >> 4, ch = (idx & 15) * 8;
      u32x4 d = *(const u32x4*)(&stage[row * XS + ch]);
      *(u32x4*)(&Qt[((size_t)b * NTOK + tokb + row) * CH + ch]) = d;
    }
    __syncthreads();
  }
  // ---- K ----
  {
    bf16x8 kw[4];
    #pragma unroll
    for (int ks = 0; ks < 4; ++ks) kw[ks] = cvt8(wk + wrow + ks * 32 + quad * 8, 1.0f);
    f32x4 acc[4];
    #pragma unroll
    for (int st = 0; st < 4; ++st) acc[st] = (f32x4){0.f, 0.f, 0.f, 0.f};
    #pragma unroll
    for (int ks = 0; ks < 4; ++ks)
      #pragma unroll
      for (int st = 0; st < 4; ++st)
        acc[st] = MFMA16(kw[ks], xfrag[st][ks], acc[st]);
    float bias[4];
    #pragma unroll
    for (int r = 0; r < 4; ++r) bias[r] = bk[w * 16 + quad * 4 + r];
    #pragma unroll
    for (int st = 0; st < 4; ++st) {
      bf16x4 o;
      #pragma unroll
      for (int r = 0; r < 4; ++r) o[r] = (bf16)(acc[st][r] + bias[r]);
      *(bf16x4*)(&stage[(st * 16 + l15) * XS + w * 16 + quad * 4]) = o;
    }
    __syncthreads();
    #pragma unroll
    for (int p = 0; p < 2; ++p) {
      int idx = p * 512 + t, row = idx >> 4, ch = (idx & 15) * 8;
      u32x4 d = *(const u32x4*)(&stage[row * XS + ch]);
      *(u32x4*)(&Kt[((size_t)b * NTOK + tokb + row) * CH + ch]) = d;
    }
    __syncthreads();
  }
  // ---- V ----
  {
    bf16x8 vw[4];
    #pragma unroll
    for (int ks = 0; ks < 4; ++ks) vw[ks] = cvt8(wv + wrow + ks * 32 + quad * 8, 1.0f);
    f32x4 acc[4];
    #pragma unroll
    for (int st = 0; st < 4; ++st) acc[st] = (f32x4){0.f, 0.f, 0.f, 0.f};
    #pragma unroll
    for (int ks = 0; ks < 4; ++ks)
      #pragma unroll
      for (int st = 0; st < 4; ++st)
        acc[st] = MFMA16(xfrag[st][ks], vw[ks], acc[st]);
    float bias = bv[w * 16 + l15];
    #pragma unroll
    for (int st = 0; st < 4; ++st) {
      bf16x4 o;
      #pragma unroll
      for (int r = 0; r < 4; ++r) o[r] = (bf16)(acc[st][r] + bias);
      *(bf16x4*)(&stage[(w * 16 + l15) * VS + st * 16 + quad * 4]) = o;
    }
    __syncthreads();
    #pragma unroll
    for (int p = 0; p < 2; ++p) {
      int idx = p * 512 + t, row = idx >> 3, tk = (idx & 7) * 8;
      u32x4 d = *(const u32x4*)(&stage[row * VS + tk]);
      *(u32x4*)(&Vt[((size_t)b * CH + row) * NTOK + tokb + tk]) = d;
    }
  }
}

// ---------------- kernel 2: flash partial, q=32/wave, DMA-dbuf kv=32 -------
// Grid = b(8) x slab(S) x qt128(32). LDS 43008 (x3 = 129K). Unified regs
// ~156 <= 160 -> 3 waves/SIMD; (256,3) cap 168 -> no spill.
__global__ __launch_bounds__(256, 3) void flash_part_kernel(
    const bf16* __restrict__ Qt, const bf16* __restrict__ Kt,
    const bf16* __restrict__ Vt, f16* __restrict__ Op, float* __restrict__ Lp,
    int nslab, int base, int rem)
{
  __shared__ __align__(16) char lds[43008];

  const int wg = blockIdx.x;
  const int qt = wg & 31;
  const int slab = (wg >> 5) % nslab;
  const int b = wg / (nslab * 32);
  const int ntile = base + (slab < rem ? 1 : 0);        // kv-32 tiles
  const int koff  = (slab * base + (slab < rem ? slab : rem)) * 32;
  const int t = threadIdx.x;
  const int w = t >> 6, lane = t & 63, quad = lane >> 4, l15 = lane & 15;
  const int swz = l15 & 7;

  bf16x8 qfrag[2][4];
  #pragma unroll
  for (int s2 = 0; s2 < 2; ++s2) {
    const bf16* qb = Qt + ((size_t)b * NTOK + qt * 128 + w * 32 + s2 * 16 + l15) * CH;
    #pragma unroll
    for (int ks = 0; ks < 4; ++ks)
      qfrag[s2][ks] = *(const bf16x8*)(qb + ks * 32 + quad * 8);
  }

  f32x4 o_acc[2][8];
  #pragma unroll
  for (int s2 = 0; s2 < 2; ++s2)
    #pragma unroll
    for (int nt = 0; nt < 8; ++nt) o_acc[s2][nt] = (f32x4){0.f, 0.f, 0.f, 0.f};
  // row-sum accumulators (MFMA vs ones-fragment; D cols all = rowsum)
  f32x4 lacc[2];
  lacc[0] = (f32x4){0.f, 0.f, 0.f, 0.f};
  lacc[1] = (f32x4){0.f, 0.f, 0.f, 0.f};
  bf16x8 ones;
  #pragma unroll
  for (int i = 0; i < 8; ++i) ones[i] = (bf16)1.0f;

  const bf16* kb = Kt + ((size_t)b * NTOK + koff) * CH;
  const bf16* vb = Vt + (size_t)b * CH * NTOK + koff;

  // DMA sources: pre-swizzled GLOBAL addresses, linear LDS dest (m173;
  // byte-identical scheme to R20/R21/R22, HW-verified).
  const bf16* kdma[2]; const bf16* vdma[2];
  #pragma unroll
  for (int jj = 0; jj < 2; ++jj) {
    int slot = w * 128 + jj * 64 + lane;
    int krow = slot >> 4, kcb = slot & 15;
    kdma[jj] = kb + (size_t)krow * CH + ((kcb ^ (krow & 7)) * 8);
    int vch = slot >> 2, vcb = slot & 3;
    vdma[jj] = vb + (size_t)vch * NTOK + (((vcb + ((vch >> 2) & 3)) & 3) * 8);
  }

  bf16* Pw = (bf16*)(lds + 32768) + w * 32 * PS2;   // per-wave [32 q][PS2]

  // prologue: DMA tile 0 -> buffer 0
  {
    bf16* dK = (bf16*)(lds) + w * 1024;
    bf16* dV = (bf16*)(lds + 8192) + w * 1024;
    dma16(kdma[0], dK); dma16(kdma[1], dK + 512);
    dma16(vdma[0], dV); dma16(vdma[1], dV + 512);
    kdma[0] += 32 * CH; kdma[1] += 32 * CH;
    vdma[0] += 32;      vdma[1] += 32;
  }
  __syncthreads();

  for (int kt = 0; kt < ntile; ++kt) {
    const char* bK = lds + ((kt & 1) ? 16384 : 0);
    const char* bV = bK + 8192;

    // issue next tile's DMA into the other buffer (its readers finished at
    // the previous barrier); the barrier at loop end drains vmcnt.
    if (kt + 1 < ntile) {
      bf16* nK = (bf16*)(lds + ((kt & 1) ? 0 : 16384)) + w * 1024;
      bf16* nV = nK + 4096;             // +8192 B = V region of that buffer
      dma16(kdma[0], nK); dma16(kdma[1], nK + 512);
      dma16(vdma[0], nV); dma16(vdma[1], nV + 512);
      kdma[0] += 32 * CH; kdma[1] += 32 * CH;
      vdma[0] += 32;      vdma[1] += 32;
    }

    // ---- S^T - FIXM = K Q^T + (-FIXM) per 16-kv strip (acc-init trick) ----
    #pragma unroll
    for (int mt = 0; mt < 2; ++mt) {
      f32x4 s[2];
      s[0] = (f32x4){-FIXM, -FIXM, -FIXM, -FIXM};
      s[1] = (f32x4){-FIXM, -FIXM, -FIXM, -FIXM};
      #pragma unroll
      for (int ks = 0; ks < 4; ++ks) {
        bf16x8 kfr = *(const bf16x8*)(bK + (mt * 16 + l15) * 256 + (((ks * 4 + quad) ^ swz) * 16));
        s[0] = MFMA16(kfr, qfrag[0][ks], s[0]);
        s[1] = MFMA16(kfr, qfrag[1][ks], s[1]);
      }
      // p = exp2(s) directly (FIXM already folded); P write b64
      #pragma unroll
      for (int s2 = 0; s2 < 2; ++s2) {
        f32x4 v = s[s2];
        bf16x4 pk;
        #pragma unroll
        for (int r = 0; r < 4; ++r) pk[r] = (bf16)exp2f(v[r]);
        *(bf16x4*)(Pw + (s2 * 16 + l15) * PS2 + mt * 16 + quad * 4) = pk;
      }
    }
    // P wave-private: wave-internal lgkmcnt orders write->read (no barrier)

    bf16x8 pfrag[2];
    #pragma unroll
    for (int s2 = 0; s2 < 2; ++s2)
      pfrag[s2] = *(const bf16x8*)(Pw + (s2 * 16 + l15) * PS2 + quad * 8);

    // row sums on the matrix pipe (replaces 10-VALU ps/lsum chain)
    lacc[0] = MFMA16(pfrag[0], ones, lacc[0]);
    lacc[1] = MFMA16(pfrag[1], ones, lacc[1]);

    // ---- O += P V (V-frag shared across both q subtiles) ----
    const int vrot = (l15 >> 2) & 3;
    const char* vrb = bV + l15 * 64 + (((quad - vrot) & 3) * 16);
    #pragma unroll
    for (int nt = 0; nt < 8; ++nt) {
      bf16x8 vfr = *(const bf16x8*)(vrb + nt * 1024);
      o_acc[0][nt] = MFMA16(pfrag[0], vfr, o_acc[0][nt]);
      o_acc[1][nt] = MFMA16(pfrag[1], vfr, o_acc[1][nt]);
    }

    __syncthreads();                    // drains vmcnt (next tile landed)
  }

  // write unnormalized partial O (fp16, plain stores) + partial row sums.
  // lacc D layout: row = quad*4+r, all cols equal -> l15==0 lanes store.
  const size_t obase = ((size_t)(slab * BATCH + b) * NTOK + qt * 128 + w * 32) * CH;
  #pragma unroll
  for (int s2 = 0; s2 < 2; ++s2)
    #pragma unroll
    for (int nt = 0; nt < 8; ++nt)
      #pragma unroll
      for (int r = 0; r < 4; ++r) {
        int row = s2 * 16 + quad * 4 + r;
        Op[obase + (size_t)row * CH + nt * 16 + l15] = (f16)o_acc[s2][nt][r];
      }
  if (l15 == 0) {
    #pragma unroll
    for (int s2 = 0; s2 < 2; ++s2)
      #pragma unroll
      for (int r = 0; r < 4; ++r)
        Lp[(size_t)(slab * BATCH + b) * NTOK + qt * 128 + w * 32 + s2 * 16 + quad * 4 + r] =
            lacc[s2][r];
  }
}

// ---------------- kernel 3: merge S slabs + Wo projection (R13-proven) -----
__global__ __launch_bounds__(256) void merge_kernel(
    const f16* __restrict__ Op, const float* __restrict__ Lp,
    const float* __restrict__ wo, const float* __restrict__ bo,
    float* __restrict__ out, int nslab)
{
  const int wg = blockIdx.x;            // 512 = b(8) x tile(64)
  const int b = wg >> 6, tile = wg & 63;
  const int t = threadIdx.x;
  const int w = t >> 6, lane = t & 63, quad = lane >> 4, l15 = lane & 15;

  __shared__ bf16 ldsO[64 * MS];        // [tok][c], padded stride (272 B)

  const size_t slabO = (size_t)BATCH * NTOK * CH;   // f16 elems per slab
  const size_t slabL = (size_t)BATCH * NTOK;
  const f16* ob = Op + ((size_t)b * NTOK + tile * 64) * CH;
  const float* lp = Lp + (size_t)b * NTOK + tile * 64;

  #pragma unroll
  for (int i = 0; i < 4; ++i) {
    int idx = t + i * 256;              // 1024 chunks of 8 elems
    int row = idx >> 4, cb = idx & 15;
    float lsum_ = 0.f;
    for (int s = 0; s < nslab; ++s) lsum_ += lp[s * slabL + row];
    float acc8[8] = {0.f, 0.f, 0.f, 0.f, 0.f, 0.f, 0.f, 0.f};
    for (int s = 0; s < nslab; ++s) {
      f16x8 a = *(const f16x8*)(ob + s * slabO + (size_t)row * CH + cb * 8);
      #pragma unroll
      for (int j = 0; j < 8; ++j) acc8[j] += (float)a[j];
    }
    float inv = 1.0f / lsum_;
    bf16 tmp[8];
    #pragma unroll
    for (int j = 0; j < 8; ++j) tmp[j] = (bf16)(acc8[j] * inv);
    *(u32x4*)(&ldsO[row * MS + cb * 8]) = *(u32x4*)tmp;
  }
  __syncthreads();

  #pragma unroll
  for (int mi = 0; mi < 2; ++mi) {
    int mt = w * 2 + mi;
    f32x4 facc[4];
    #pragma unroll
    for (int nt = 0; nt < 4; ++nt) facc[nt] = (f32x4){0.f, 0.f, 0.f, 0.f};
    #pragma unroll
    for (int ks = 0; ks < 4; ++ks) {
      bf16x8 afr = cvt8(wo + (size_t)(mt * 16 + l15) * CH + ks * 32 + quad * 8, 1.0f);
      #pragma unroll
      for (int nt = 0; nt < 4; ++nt) {
        bf16x8 bfr = *(const bf16x8*)(&ldsO[(nt * 16 + l15) * MS + ks * 32 + quad * 8]);
        facc[nt] = MFMA16(afr, bfr, facc[nt]);
      }
    }
    #pragma unroll
    for (int nt = 0; nt < 4; ++nt) {
      int n = tile * 64 + nt * 16 + l15;
      #pragma unroll
      for (int r = 0; r < 4; ++r) {
        int o = mt * 16 + quad * 4 + r;
        out[((size_t)b * CH + o) * NTOK + n] = facc[nt][r] + bo[o];
      }
    }
  }
}

// ---------------- launch ---------------------------------------------------
extern "C" void kernel_launch(void* const* d_in, const int* in_sizes, int n_in,
                              void* d_out, int out_size, void* d_ws, size_t ws_size,
                              hipStream_t stream)
{
  const float* x  = (const float*)d_in[0];
  const float* fw = (const float*)d_in[1];
  const float* wq = (const float*)d_in[2];
  const float* bq = (const float*)d_in[3];
  const float* wk = (const float*)d_in[4];
  const float* bk = (const float*)d_in[5];
  const float* wv = (const float*)d_in[6];
  const float* bv = (const float*)d_in[7];
  const float* wo = (const float*)d_in[8];
  const float* bo = (const float*)d_in[9];
  float* out = (float*)d_out;

  char* ws = (char*)d_ws;
  bf16*  Qt  = (bf16*)ws;                              // 8 MB
  bf16*  Kt  = Qt + (size_t)BATCH * NTOK * CH;         // 8 MB
  bf16*  Vt  = Kt + (size_t)BATCH * NTOK * CH;         // 8 MB
  f16*   Op  = (f16*)(ws + 3ull * 8388608);            // S x 8 MB fp16 slabs

  // S=3 (grid 768 = one pass at 3 WG/CU) if ws allows, else S=2 (grid 512).
  const size_t qkv_bytes = 3ull * 8388608;
  const size_t need3 = qkv_bytes + 3ull * ((size_t)BATCH * NTOK * CH * 2 + (size_t)BATCH * NTOK * 4);
  const int S = (ws_size >= need3) ? 3 : 2;
  const int base = 128 / S, rem = 128 % S;             // kv-32 tiles per slab

  float* Lp = (float*)((char*)Op + (size_t)S * BATCH * NTOK * CH * 2);

  // 1/sqrt(128) * log2(e): exp2-domain scale folded into Wq/bq
  const float qscale = 0.08838834764831845f * 1.44269504f;

  proj_kernel<<<512, 512, 0, stream>>>(x, fw, wq, wk, wv,
                                       bq, bk, bv, Qt, Kt, Vt, qscale);
  flash_part_kernel<<<BATCH * S * 32, 256, 0, stream>>>(Qt, Kt, Vt, Op, Lp,
                                                        S, base, rem);
  merge_kernel<<<512, 256, 0, stream>>>(Op, Lp, wo, bo, out, S);
}